// Round 15
// baseline (440.878 us; speedup 1.0000x reference)
//
#include <hip/hip_runtime.h>
#include <hip/hip_fp16.h>
#include <hip/hip_cooperative_groups.h>

namespace cg = cooperative_groups;

#define EPSF 1e-7f
#define MAXNORM (1.0f - 1e-5f)

__device__ __forceinline__ float rsum64(float v) {
#pragma unroll
  for (int m = 32; m; m >>= 1) v += __shfl_xor(v, m, 64);
  return v;
}
__device__ __forceinline__ float rsum16(float v) {
#pragma unroll
  for (int m = 8; m; m >>= 1) v += __shfl_xor(v, m, 64);
  return v;
}
__device__ __forceinline__ float gr8(float v) {
  v += __shfl_xor(v, 1, 64);
  v += __shfl_xor(v, 2, 64);
  v += __shfl_xor(v, 4, 64);
  return v;
}

__device__ __forceinline__ float frcp(float x) { return __builtin_amdgcn_rcpf(x); }
__device__ __forceinline__ float fsqrt_(float x) { return __builtin_amdgcn_sqrtf(x); }
__device__ __forceinline__ float tanh_fast(float x) {
  x = fminf(x, 20.f);
  float e = __builtin_amdgcn_exp2f(x * 2.88539008178f);  // e^{2x}
  return (e - 1.f) * frcp(e + 1.f);
}
__device__ __forceinline__ float atanh_fast(float x) {
  return 0.34657359028f * __builtin_amdgcn_logf((1.f + x) * frcp(1.f - x));
}
__device__ __forceinline__ float lp_exp_log_scale(float nu) {
  float te = tanh_fast(nu);
  float tec = fminf(fmaxf(te, EPSF), MAXNORM);
  return atanh_fast(tec) * frcp(fmaxf(te, EPSF)) * te * frcp(nu);
}

__device__ __forceinline__ float4 ld4(const float* p) {
  return *reinterpret_cast<const float4*>(p);
}

__device__ __forceinline__ void hb_from_b(const float* __restrict__ b, int sub,
                                          float hb8[8], float& hb2) {
  float4 b0 = ld4(b + sub * 8), b1 = ld4(b + sub * 8 + 4);
  float bb8[8] = {b0.x, b0.y, b0.z, b0.w, b1.x, b1.y, b1.z, b1.w};
  float p = 0.f;
#pragma unroll
  for (int j = 0; j < 8; ++j) p = fmaf(bb8[j], bb8[j], p);
  p = gr8(p);
  float nb = fmaxf(fsqrt_(p), EPSF);
  float cb = fminf(tanh_fast(nb), MAXNORM);
  float kb = cb * frcp(nb);
#pragma unroll
  for (int j = 0; j < 8; ++j) hb8[j] = kb * bb8[j];
  hb2 = cb * cb;
}

// 8-node gather over fp16 rows, node-major ushort csr, index software-pipelined.
__device__ __forceinline__ void gather8h(const unsigned short* __restrict__ csr,
                                         const __half* __restrict__ xtp,
                                         int r0, int deg, int g, int sub,
                                         float acc[8]) {
  const uint4* xt4 = reinterpret_cast<const uint4*>(xtp);
  int lb = g << 3;
  int cur = (sub < deg) ? (int)csr[r0 + sub] : 0;
  for (int j0 = 0; j0 < deg; j0 += 8) {
    int nj = j0 + 8;
    int nxt = (nj + sub < deg) ? (int)csr[r0 + nj + sub] : 0;
#pragma unroll
    for (int m = 0; m < 8; ++m) {
      int idx = __shfl(cur, lb + m, 64);
      float msk = (j0 + m < deg) ? 1.f : 0.f;
      union { uint4 u; __half2 h[4]; } U;
      U.u = xt4[(size_t)idx * 8 + sub];
      float2 f0 = __half22float2(U.h[0]);
      float2 f1 = __half22float2(U.h[1]);
      float2 f2 = __half22float2(U.h[2]);
      float2 f3 = __half22float2(U.h[3]);
      acc[0] = fmaf(msk, f0.x, acc[0]); acc[1] = fmaf(msk, f0.y, acc[1]);
      acc[2] = fmaf(msk, f1.x, acc[2]); acc[3] = fmaf(msk, f1.y, acc[3]);
      acc[4] = fmaf(msk, f2.x, acc[4]); acc[5] = fmaf(msk, f2.y, acc[5]);
      acc[6] = fmaf(msk, f3.x, acc[6]); acc[7] = fmaf(msk, f3.y, acc[7]);
    }
    cur = nxt;
  }
}

__device__ __forceinline__ void st8h(__half* __restrict__ xt, int node, int sub,
                                     const float o[8]) {
  union { uint4 u; __half2 h[4]; } U;
  U.h[0] = __floats2half2_rn(o[0], o[1]);
  U.h[1] = __floats2half2_rn(o[2], o[3]);
  U.h[2] = __floats2half2_rn(o[4], o[5]);
  U.h[3] = __floats2half2_rn(o[6], o[7]);
  reinterpret_cast<uint4*>(xt)[(size_t)node * 8 + sub] = U.u;
}

__device__ __forceinline__ void linear_tail8(
    const float* __restrict__ Wl, float* __restrict__ sc, int g, int sub,
    int lane, const float t2[8], const float hb8[8], float hb2, float out8[8]) {
  float4* sw = reinterpret_cast<float4*>(sc + g * 68 + sub * 8);
  sw[0] = make_float4(t2[0], t2[1], t2[2], t2[3]);
  sw[1] = make_float4(t2[4], t2[5], t2[6], t2[7]);
  float y[8] = {0.f, 0.f, 0.f, 0.f, 0.f, 0.f, 0.f, 0.f};
  const float4* Wrow = reinterpret_cast<const float4*>(Wl + lane * 68);
#pragma unroll
  for (int q = 0; q < 16; ++q) {
    float4 w = Wrow[q];
#pragma unroll
    for (int g2 = 0; g2 < 8; ++g2) {
      float4 tq = *reinterpret_cast<const float4*>(sc + g2 * 68 + q * 4);
      y[g2] = fmaf(w.x, tq.x, fmaf(w.y, tq.y, fmaf(w.z, tq.z, fmaf(w.w, tq.w, y[g2]))));
    }
  }
#pragma unroll
  for (int g2 = 0; g2 < 8; ++g2) sc[g2 * 68 + lane] = y[g2];
  float4 r0 = *reinterpret_cast<const float4*>(sc + g * 68 + sub * 8);
  float4 r1 = *reinterpret_cast<const float4*>(sc + g * 68 + sub * 8 + 4);
  float yv[8] = {r0.x, r0.y, r0.z, r0.w, r1.x, r1.y, r1.z, r1.w};
  float p1 = 0.f, p2 = 0.f;
#pragma unroll
  for (int j = 0; j < 8; ++j) {
    p1 = fmaf(yv[j], yv[j], p1);
    p2 = fmaf(yv[j], hb8[j], p2);
  }
  p1 = gr8(p1); p2 = gr8(p2);
  float ny = fmaxf(fsqrt_(p1), EPSF);
  float cy = fminf(tanh_fast(ny), MAXNORM);
  float k = cy * frcp(ny);
  float xy = k * p2;
  float x2 = cy * cy;
  float aa = 1.f + 2.f * xy + hb2;
  float cc = 1.f - x2;
  float den = fmaxf(1.f + 2.f * xy + x2 * hb2, EPSF);
  float rd = frcp(den);
  float nr2 = (aa * aa * x2 + 2.f * aa * cc * xy + cc * cc * hb2) * rd * rd;
  float nr = fmaxf(fsqrt_(nr2), EPSF);
  float s = atanh_fast(fminf(nr, MAXNORM)) * frcp(nr);
  float sk = s * rd;
#pragma unroll
  for (int j = 0; j < 8; ++j) out8[j] = sk * (aa * k * yv[j] + cc * hb8[j]);
}

struct CoopArgs {
  const int* src; const int* dst; const int* batch;
  const float* x;
  const float* W1; const float* b1;
  const float* W2; const float* b2;
  const float* W3; const float* b3;
  const float* W4; const float* b4;
  int* deg8; int* offs8; int* locscan; int* rowptr; int* partial;
  int* rank; unsigned short* csr;
  __half* xtA; __half* xtB;
  float* pooled; float* cntg; float* out;
  int N, E, G;
};

// One cooperative kernel = the whole pipeline. All phases grid-stride; no
// early returns (every thread reaches every grid.sync).
__global__ void __launch_bounds__(512) k_coop(CoopArgs a) {
  cg::grid_group grid = cg::this_grid();
  __shared__ __align__(16) float Wl[64 * 68];
  __shared__ __align__(16) float sc_all[8][8 * 68];
  __shared__ int ibuf[512];

  const int tid = threadIdx.x;
  const int wid = tid >> 6, lane = tid & 63;
  const int g = lane >> 3, sub = lane & 7;
  const int gsz = gridDim.x;
  const int N = a.N, E = a.E, G = a.G;
  const int gstride = gsz * 512;
  int gbase = blockIdx.x * 512 + tid;

  // P0: zero deg8 (8N) and pooled (G*64)
  for (int i = gbase; i < 8 * N; i += gstride) a.deg8[i] = 0;
  for (int i = gbase; i < G * 64; i += gstride) a.pooled[i] = 0.f;
  grid.sync();

  // P1: XCD-private hist + rank capture; graph sizes via binary search
  for (int e = gbase; e < E; e += gstride) {
    int c = (e >> 8) & 7;
    a.rank[e] = atomicAdd(&a.deg8[(size_t)c * N + a.dst[e]], 1);
  }
  for (int gg = gbase; gg < G; gg += gstride) {
    int lo = 0, hi = N;
    while (lo < hi) { int mid = (lo + hi) >> 1; if (a.batch[mid] < gg) lo = mid + 1; else hi = mid; }
    int lb2 = lo;
    lo = 0; hi = N; int g1 = gg + 1;
    while (lo < hi) { int mid = (lo + hi) >> 1; if (a.batch[mid] < g1) lo = mid + 1; else hi = mid; }
    a.cntg[gg] = (float)(lo - lb2);
  }
  grid.sync();

  // P2: per-node 8-copy reduce + offs8 + block-local scan (512-wide)
  int nbP = (N + 511) / 512;
  for (int blk = blockIdx.x; blk < nbP; blk += gsz) {
    int i = blk * 512 + tid;
    int s = 0;
    if (i < N) {
#pragma unroll
      for (int k = 0; k < 8; ++k) {
        int v = a.deg8[(size_t)k * N + i];
        a.offs8[(size_t)k * N + i] = s;
        s += v;
      }
    }
    int v0 = s;
    __syncthreads();
    ibuf[tid] = v0;
    __syncthreads();
#pragma unroll
    for (int off = 1; off < 512; off <<= 1) {
      int t = (tid >= off) ? ibuf[tid - off] : 0;
      __syncthreads();
      ibuf[tid] += t;
      __syncthreads();
    }
    if (i < N) a.locscan[i] = ibuf[tid] - v0;
    if (tid == 511) a.partial[blk] = ibuf[511];
  }
  grid.sync();

  // P3: single-block exclusive scan of partials (nbP <= 512)
  if (blockIdx.x == 0) {
    int v = (tid < nbP) ? a.partial[tid] : 0;
    ibuf[tid] = v;
    __syncthreads();
#pragma unroll
    for (int off = 1; off < 512; off <<= 1) {
      int t = (tid >= off) ? ibuf[tid - off] : 0;
      __syncthreads();
      ibuf[tid] += t;
      __syncthreads();
    }
    if (tid < nbP) a.partial[tid] = ibuf[tid] - v;
  }
  grid.sync();

  // P4: rowptr = locscan + partial[blk]
  for (int blk = blockIdx.x; blk < nbP; blk += gsz) {
    int i = blk * 512 + tid;
    if (i < N) a.rowptr[i] = a.locscan[i] + a.partial[blk];
  }
  if (blockIdx.x == 0 && tid == 0) a.rowptr[N] = E;
  grid.sync();

  // P5: atomic-free CSR fill  +  layer-1 linear (x -> xtA)
  for (int e = gbase; e < E; e += gstride) {
    int c = (e >> 8) & 7;
    int d = a.dst[e];
    a.csr[a.rowptr[d] + a.offs8[(size_t)c * N + d] + a.rank[e]] =
        (unsigned short)a.src[e];
  }
  for (int i = tid; i < 4096; i += 512) Wl[(i >> 6) * 68 + (i & 63)] = a.W1[i];
  __syncthreads();
  {
    float hb8[8], hb2;
    hb_from_b(a.b1, sub, hb8, hb2);
    int nbL = (N + 63) / 64;
    for (int blk = blockIdx.x; blk < nbL; blk += gsz) {
      int slot = blk * 64 + wid * 8 + g;
      bool valid = slot < N;
      int node = valid ? slot : 0;
      const float* row = a.x + (size_t)node * 64 + sub * 8;
      float4 v0 = ld4(row), v1 = ld4(row + 4);
      float xa[8] = {v0.x, v0.y, v0.z, v0.w, v1.x, v1.y, v1.z, v1.w};
      float p = 0.f;
#pragma unroll
      for (int j = 0; j < 8; ++j) p = fmaf(xa[j], xa[j], p);
      p = gr8(p);
      float na = fmaxf(fsqrt_(p), EPSF);
      float sc1 = lp_exp_log_scale(na);
      float t2[8];
#pragma unroll
      for (int j = 0; j < 8; ++j) t2[j] = sc1 * xa[j];
      float out8[8];
      linear_tail8(Wl, sc_all[wid], g, sub, lane, t2, hb8, hb2, out8);
      if (valid) st8h(a.xtA, node, sub, out8);
    }
  }
  grid.sync();

  // P6/P7: two gather+linear layers
  for (int layer = 0; layer < 2; ++layer) {
    const float* W = (layer == 0) ? a.W2 : a.W3;
    const float* b = (layer == 0) ? a.b2 : a.b3;
    const __half* xin = (layer == 0) ? a.xtA : a.xtB;
    __half* xout = (layer == 0) ? a.xtB : a.xtA;
    for (int i = tid; i < 4096; i += 512) Wl[(i >> 6) * 68 + (i & 63)] = W[i];
    __syncthreads();
    float hb8[8], hb2;
    hb_from_b(b, sub, hb8, hb2);
    int nbL = (N + 63) / 64;
    for (int blk = blockIdx.x; blk < nbL; blk += gsz) {
      int slot = blk * 64 + wid * 8 + g;
      bool valid = slot < N;
      int node = valid ? slot : 0;
      int r0 = a.rowptr[node];
      int deg = valid ? (a.rowptr[node + 1] - r0) : 0;
      float acc[8] = {0.f, 0.f, 0.f, 0.f, 0.f, 0.f, 0.f, 0.f};
      gather8h(a.csr, xin, r0, deg, g, sub, acc);
      float rdeg = frcp(fmaxf((float)deg, 1.f));
      float u[8];
#pragma unroll
      for (int j = 0; j < 8; ++j) u[j] = acc[j] * rdeg;
      float p = 0.f, q = 0.f;
#pragma unroll
      for (int j = 0; j < 8; ++j) {
        float w = (u[j] < 0.f) ? 0.04f : 1.f;
        p = fmaf(u[j], u[j], p);
        q = fmaf(w * u[j], u[j], q);
      }
      p = gr8(p); q = gr8(q);
      float nu = fmaxf(fsqrt_(p), EPSF);
      float s1 = lp_exp_log_scale(nu);
      float nt = fmaxf(s1 * fsqrt_(q), EPSF);
      float f = lp_exp_log_scale(nt) * s1;
      float t2[8];
#pragma unroll
      for (int j = 0; j < 8; ++j) t2[j] = f * u[j] * ((u[j] < 0.f) ? 0.2f : 1.f);
      float out8[8];
      linear_tail8(Wl, sc_all[wid], g, sub, lane, t2, hb8, hb2, out8);
      if (valid) st8h(xout, node, sub, out8);
    }
    grid.sync();
  }

  // P8: gather + logmap + pool (xtA -> pooled)
  {
    int nbL = (N + 63) / 64;
    for (int blk = blockIdx.x; blk < nbL; blk += gsz) {
      int slot = blk * 64 + wid * 8 + g;
      bool valid = slot < N;
      int node = valid ? slot : 0;
      int r0 = a.rowptr[node];
      int deg = valid ? (a.rowptr[node + 1] - r0) : 0;
      float acc[8] = {0.f, 0.f, 0.f, 0.f, 0.f, 0.f, 0.f, 0.f};
      gather8h(a.csr, a.xtA, r0, deg, g, sub, acc);
      float rdeg = frcp(fmaxf((float)deg, 1.f));
      float u[8], p = 0.f;
#pragma unroll
      for (int j = 0; j < 8; ++j) {
        u[j] = acc[j] * rdeg;
        p = fmaf(u[j], u[j], p);
      }
      p = gr8(p);
      float nu = fmaxf(fsqrt_(p), EPSF);
      float s = lp_exp_log_scale(nu);
      float t8[8];
#pragma unroll
      for (int j = 0; j < 8; ++j) t8[j] = (valid ? s : 0.f) * u[j];
      int bs = a.batch[node];
      int b0 = __shfl(bs, 0, 64);
      bool uniform = __all(valid && bs == b0);
      if (uniform) {
#pragma unroll
        for (int j = 0; j < 8; ++j) {
          t8[j] += __shfl_xor(t8[j], 8, 64);
          t8[j] += __shfl_xor(t8[j], 16, 64);
          t8[j] += __shfl_xor(t8[j], 32, 64);
        }
        if (g == 0) {
#pragma unroll
          for (int j = 0; j < 8; ++j)
            atomicAdd(&a.pooled[(size_t)b0 * 64 + sub * 8 + j], t8[j]);
        }
      } else if (valid) {
#pragma unroll
        for (int j = 0; j < 8; ++j)
          atomicAdd(&a.pooled[(size_t)bs * 64 + sub * 8 + j], t8[j]);
      }
    }
  }
  grid.sync();

  // P9: head, one wave per graph (precise libm; negligible cost)
  for (int gi = blockIdx.x * 8 + wid; gi < G; gi += gsz * 8) {
    float u = a.pooled[(size_t)gi * 64 + lane] / fmaxf(a.cntg[gi], 1.0f);
    float n = fmaxf(sqrtf(rsum64(u * u)), EPSF);
    float e = tanhf(n) * u / n;
    float ne = fmaxf(sqrtf(rsum64(e * e)), EPSF);
    if (ne > MAXNORM) e *= MAXNORM / ne;
    float nn = fmaxf(sqrtf(rsum64(e * e)), EPSF);
    float t = atanhf(fminf(nn, MAXNORM)) * e / nn;

    int row = lane & 15;
    float acc = 0.f;
#pragma unroll
    for (int k = 0; k < 64; ++k) {
      float tk = __shfl(t, k, 64);
      acc = fmaf(a.W4[row * 64 + k], tk, acc);
    }
    float ny = fmaxf(sqrtf(rsum16(acc * acc)), EPSF);
    float hy = tanhf(ny) * acc / ny;
    float nh = fmaxf(sqrtf(rsum16(hy * hy)), EPSF);
    if (nh > MAXNORM) hy *= MAXNORM / nh;
    float bb = a.b4[row];
    float nb = fmaxf(sqrtf(rsum16(bb * bb)), EPSF);
    float hb = tanhf(nb) * bb / nb;
    float nhb = fmaxf(sqrtf(rsum16(hb * hb)), EPSF);
    if (nhb > MAXNORM) hb *= MAXNORM / nhb;
    float x2 = rsum16(hy * hy);
    float y2 = rsum16(hb * hb);
    float xy = rsum16(hy * hb);
    float num = (1.f + 2.f * xy + y2) * hy + (1.f - x2) * hb;
    float den = fmaxf(1.f + 2.f * xy + x2 * y2, EPSF);
    float r = num / den;
    float nr = fmaxf(sqrtf(rsum16(r * r)), EPSF);
    if (nr > MAXNORM) r *= MAXNORM / nr;
    if (lane < 16) a.out[(size_t)gi * 16 + lane] = r;
  }
}

extern "C" void kernel_launch(void* const* d_in, const int* in_sizes, int n_in,
                              void* d_out, int out_size, void* d_ws, size_t ws_size,
                              hipStream_t stream) {
  int N = in_sizes[0] / 64;
  int E = in_sizes[9] / 2;
  int G = out_size / 16;
  const int* ei = (const int*)d_in[9];

  float* ws = (float*)d_ws;
  __half* xtA   = (__half*)ws;                 // N*64 halves
  __half* xtB   = xtA + (size_t)N * 64;        // N*64 halves
  float* pooled = ws + (size_t)N * 64;         // G*64
  float* cntg   = pooled + (size_t)G * 64;     // G
  int* ip       = (int*)(cntg + G);
  int* deg8     = ip;                          // 8N
  int* offs8    = deg8 + (size_t)8 * N;        // 8N
  int* locscan  = offs8 + (size_t)8 * N;       // N
  int* rowptr   = locscan + N;                 // N+1
  int* partial  = rowptr + N + 1;              // 512 (pad)
  int* rank     = partial + 512;               // E
  unsigned short* csr = (unsigned short*)(rank + E);  // E ushorts

  CoopArgs a;
  a.src = ei; a.dst = ei + E; a.batch = (const int*)d_in[10];
  a.x = (const float*)d_in[0];
  a.W1 = (const float*)d_in[1]; a.b1 = (const float*)d_in[2];
  a.W2 = (const float*)d_in[3]; a.b2 = (const float*)d_in[4];
  a.W3 = (const float*)d_in[5]; a.b3 = (const float*)d_in[6];
  a.W4 = (const float*)d_in[7]; a.b4 = (const float*)d_in[8];
  a.deg8 = deg8; a.offs8 = offs8; a.locscan = locscan; a.rowptr = rowptr;
  a.partial = partial; a.rank = rank; a.csr = csr;
  a.xtA = xtA; a.xtB = xtB; a.pooled = pooled; a.cntg = cntg;
  a.out = (float*)d_out;
  a.N = N; a.E = E; a.G = G;

  int nbL = (N + 63) / 64;
  int perCU = 0;
  hipOccupancyMaxActiveBlocksPerMultiprocessor(&perCU, k_coop, 512, 0);
  if (perCU < 1) perCU = 1;
  int dev = 0, numCU = 256;
  hipGetDevice(&dev);
  hipDeviceGetAttribute(&numCU, hipDeviceAttributeMultiprocessorCount, dev);
  int cap = perCU * numCU;
  int grid = (nbL < cap) ? nbL : cap;

  void* params[] = {&a};
  hipLaunchCooperativeKernel((const void*)k_coop, dim3(grid), dim3(512),
                             params, 0, stream);
}

// Round 16
// 201.546 us; speedup vs baseline: 2.1875x; 2.1875x over previous
//
#include <hip/hip_runtime.h>
#include <hip/hip_fp16.h>

#define EPSF 1e-7f
#define MAXNORM (1.0f - 1e-5f)

__device__ __forceinline__ float rsum64(float v) {
#pragma unroll
  for (int m = 32; m; m >>= 1) v += __shfl_xor(v, m, 64);
  return v;
}
__device__ __forceinline__ float rsum16(float v) {
#pragma unroll
  for (int m = 8; m; m >>= 1) v += __shfl_xor(v, m, 64);
  return v;
}
// 8-lane group reduce (3 levels) — serves 8 nodes per wave at once
__device__ __forceinline__ float gr8(float v) {
  v += __shfl_xor(v, 1, 64);
  v += __shfl_xor(v, 2, 64);
  v += __shfl_xor(v, 4, 64);
  return v;
}

__device__ __forceinline__ float frcp(float x) { return __builtin_amdgcn_rcpf(x); }
__device__ __forceinline__ float fsqrt_(float x) { return __builtin_amdgcn_sqrtf(x); }
__device__ __forceinline__ float tanh_fast(float x) {
  x = fminf(x, 20.f);
  float e = __builtin_amdgcn_exp2f(x * 2.88539008178f);  // e^{2x}
  return (e - 1.f) * frcp(e + 1.f);
}
__device__ __forceinline__ float atanh_fast(float x) {
  return 0.34657359028f * __builtin_amdgcn_logf((1.f + x) * frcp(1.f - x));
}
// logmap0(proj(expmap0(u))) == f(nu) * u
__device__ __forceinline__ float lp_exp_log_scale(float nu) {
  float te = tanh_fast(nu);
  float tec = fminf(fmaxf(te, EPSF), MAXNORM);
  return atanh_fast(tec) * frcp(fmaxf(te, EPSF)) * te * frcp(nu);
}

__device__ __forceinline__ float4 ld4(const float* p) {
  return *reinterpret_cast<const float4*>(p);
}

// hb8/hb2 = proj(expmap0(b)) in 8-dim layout, computed per-thread (~20 VALU).
__device__ __forceinline__ void hb_from_b(const float* __restrict__ b, int sub,
                                          float hb8[8], float& hb2) {
  float4 b0 = ld4(b + sub * 8), b1 = ld4(b + sub * 8 + 4);
  float bb8[8] = {b0.x, b0.y, b0.z, b0.w, b1.x, b1.y, b1.z, b1.w};
  float p = 0.f;
#pragma unroll
  for (int j = 0; j < 8; ++j) p = fmaf(bb8[j], bb8[j], p);
  p = gr8(p);
  float nb = fmaxf(fsqrt_(p), EPSF);
  float cb = fminf(tanh_fast(nb), MAXNORM);
  float kb = cb * frcp(nb);
#pragma unroll
  for (int j = 0; j < 8; ++j) hb8[j] = kb * bb8[j];
  hb2 = cb * cb;
}

// 8-node gather over fp16 rows, node-major ushort csr, index software-pipelined.
__device__ __forceinline__ void gather8h(const unsigned short* __restrict__ csr,
                                         const __half* __restrict__ xtp,
                                         int r0, int deg, int g, int sub,
                                         float acc[8]) {
  const uint4* xt4 = reinterpret_cast<const uint4*>(xtp);
  int lb = g << 3;
  int cur = (sub < deg) ? (int)csr[r0 + sub] : 0;
  for (int j0 = 0; j0 < deg; j0 += 8) {
    int nj = j0 + 8;
    int nxt = (nj + sub < deg) ? (int)csr[r0 + nj + sub] : 0;
#pragma unroll
    for (int m = 0; m < 8; ++m) {
      int idx = __shfl(cur, lb + m, 64);
      float msk = (j0 + m < deg) ? 1.f : 0.f;
      union { uint4 u; __half2 h[4]; } U;
      U.u = xt4[(size_t)idx * 8 + sub];
      float2 f0 = __half22float2(U.h[0]);
      float2 f1 = __half22float2(U.h[1]);
      float2 f2 = __half22float2(U.h[2]);
      float2 f3 = __half22float2(U.h[3]);
      acc[0] = fmaf(msk, f0.x, acc[0]); acc[1] = fmaf(msk, f0.y, acc[1]);
      acc[2] = fmaf(msk, f1.x, acc[2]); acc[3] = fmaf(msk, f1.y, acc[3]);
      acc[4] = fmaf(msk, f2.x, acc[4]); acc[5] = fmaf(msk, f2.y, acc[5]);
      acc[6] = fmaf(msk, f3.x, acc[6]); acc[7] = fmaf(msk, f3.y, acc[7]);
    }
    cur = nxt;
  }
}

// store 8 f32 dims as 8 fp16 (one uint4 per lane)
__device__ __forceinline__ void st8h(__half* __restrict__ xt, int node, int sub,
                                     const float o[8]) {
  union { uint4 u; __half2 h[4]; } U;
  U.h[0] = __floats2half2_rn(o[0], o[1]);
  U.h[1] = __floats2half2_rn(o[2], o[3]);
  U.h[2] = __floats2half2_rn(o[4], o[5]);
  U.h[3] = __floats2half2_rn(o[6], o[7]);
  reinterpret_cast<uint4*>(xt)[(size_t)node * 8 + sub] = U.u;
}

// ---- matvec + mobius-bias + proj + logmap0, 8 nodes/wave, 8-dim layout.
__device__ __forceinline__ void linear_tail8(
    const float* __restrict__ Wl, float* __restrict__ sc, int g, int sub,
    int lane, const float t2[8], const float hb8[8], float hb2, float out8[8]) {
  float4* sw = reinterpret_cast<float4*>(sc + g * 68 + sub * 8);
  sw[0] = make_float4(t2[0], t2[1], t2[2], t2[3]);
  sw[1] = make_float4(t2[4], t2[5], t2[6], t2[7]);
  float y[8] = {0.f, 0.f, 0.f, 0.f, 0.f, 0.f, 0.f, 0.f};
  const float4* Wrow = reinterpret_cast<const float4*>(Wl + lane * 68);
#pragma unroll
  for (int q = 0; q < 16; ++q) {
    float4 w = Wrow[q];
#pragma unroll
    for (int g2 = 0; g2 < 8; ++g2) {
      float4 tq = *reinterpret_cast<const float4*>(sc + g2 * 68 + q * 4);
      y[g2] = fmaf(w.x, tq.x, fmaf(w.y, tq.y, fmaf(w.z, tq.z, fmaf(w.w, tq.w, y[g2]))));
    }
  }
#pragma unroll
  for (int g2 = 0; g2 < 8; ++g2) sc[g2 * 68 + lane] = y[g2];
  float4 r0 = *reinterpret_cast<const float4*>(sc + g * 68 + sub * 8);
  float4 r1 = *reinterpret_cast<const float4*>(sc + g * 68 + sub * 8 + 4);
  float yv[8] = {r0.x, r0.y, r0.z, r0.w, r1.x, r1.y, r1.z, r1.w};
  float p1 = 0.f, p2 = 0.f;
#pragma unroll
  for (int j = 0; j < 8; ++j) {
    p1 = fmaf(yv[j], yv[j], p1);
    p2 = fmaf(yv[j], hb8[j], p2);
  }
  p1 = gr8(p1); p2 = gr8(p2);
  float ny = fmaxf(fsqrt_(p1), EPSF);
  float cy = fminf(tanh_fast(ny), MAXNORM);
  float k = cy * frcp(ny);
  float xy = k * p2;
  float x2 = cy * cy;
  float aa = 1.f + 2.f * xy + hb2;
  float cc = 1.f - x2;
  float den = fmaxf(1.f + 2.f * xy + x2 * hb2, EPSF);
  float rd = frcp(den);
  float nr2 = (aa * aa * x2 + 2.f * aa * cc * xy + cc * cc * hb2) * rd * rd;
  float nr = fmaxf(fsqrt_(nr2), EPSF);
  float s = atanh_fast(fminf(nr, MAXNORM)) * frcp(nr);
  float sk = s * rd;
#pragma unroll
  for (int j = 0; j < 8; ++j) out8[j] = sk * (aa * k * yv[j] + cc * hb8[j]);
}

// ---- fused: XCD-private hist + rank capture | graph sizes (block-range split)
__global__ void __launch_bounds__(256) k_histg(
    const int* __restrict__ dst, int* __restrict__ deg8, int* __restrict__ rank,
    int E, int N, const int* __restrict__ batch, float* __restrict__ cntg,
    int G, int nbE) {
  if ((int)blockIdx.x < nbE) {
    int e = blockIdx.x * 256 + threadIdx.x;
    if (e >= E) return;
    int c = (e >> 8) & 7;
    rank[e] = atomicAdd(&deg8[(size_t)c * N + dst[e]], 1);
  } else {
    int g = (blockIdx.x - nbE) * 256 + threadIdx.x;
    if (g >= G) return;
    int lo = 0, hi = N;
    while (lo < hi) { int mid = (lo + hi) >> 1; if (batch[mid] < g) lo = mid + 1; else hi = mid; }
    int lb = lo;
    lo = 0; hi = N; int g1 = g + 1;
    while (lo < hi) { int mid = (lo + hi) >> 1; if (batch[mid] < g1) lo = mid + 1; else hi = mid; }
    cntg[g] = (float)(lo - lb);
  }
}

// ---- fused scan: per-node 8-copy reduce + offs8 + block scan; the LAST
// block to finish scans the partials and applies rowptr itself (and zeroes
// pooled). Replaces scanAR+scanB+scanC+memset(pooled) = 3 dispatches saved.
// (R15 lesson: grid.sync is ~50µs on this chip; last-block-finish has ONE
// device-scope atomic and no grid-wide spin.)
__global__ void __launch_bounds__(512) k_scanR(
    const int* __restrict__ deg8, int* __restrict__ offs8,
    int* __restrict__ locscan, int* __restrict__ rowptr,
    int* __restrict__ partial, int* __restrict__ done,
    float* __restrict__ pooled, int N, int E, int PG) {
  __shared__ int ibuf[512];
  __shared__ int amlast;
  int nbP = (int)gridDim.x;  // == ceil(N/512)
  int tid = threadIdx.x;
  int blk = blockIdx.x;
  int i = blk * 512 + tid;
  int s = 0;
  if (i < N) {
#pragma unroll
    for (int k = 0; k < 8; ++k) {
      int v = deg8[(size_t)k * N + i];
      offs8[(size_t)k * N + i] = s;
      s += v;
    }
  }
  int v0 = s;
  ibuf[tid] = v0;
  __syncthreads();
#pragma unroll
  for (int off = 1; off < 512; off <<= 1) {
    int t = (tid >= off) ? ibuf[tid - off] : 0;
    __syncthreads();
    ibuf[tid] += t;
    __syncthreads();
  }
  if (i < N) locscan[i] = ibuf[tid] - v0;
  if (tid == 511) partial[blk] = ibuf[511];
  __threadfence();  // make locscan/partial visible device-wide (release)
  __syncthreads();
  if (tid == 0) amlast = (atomicAdd(done, 1) == nbP - 1) ? 1 : 0;
  __syncthreads();
  if (!amlast) return;
  __threadfence();  // acquire side before reading other blocks' data
  // scan partials (nbP <= 512)
  int pv = (tid < nbP) ? partial[tid] : 0;
  ibuf[tid] = pv;
  __syncthreads();
#pragma unroll
  for (int off = 1; off < 512; off <<= 1) {
    int t = (tid >= off) ? ibuf[tid - off] : 0;
    __syncthreads();
    ibuf[tid] += t;
    __syncthreads();
  }
  if (tid < nbP) partial[tid] = ibuf[tid] - pv;
  __syncthreads();
  for (int j = tid; j < N; j += 512)
    rowptr[j] = locscan[j] + partial[j >> 9];
  if (tid == 0) rowptr[N] = E;
  for (int j = tid; j < PG; j += 512) pooled[j] = 0.f;
}

// ---- fused: atomic-free CSR fill (blocks < nbF) | layer-1 linear (rest).
__global__ void __launch_bounds__(512) k_filllin(
    const int* __restrict__ src, const int* __restrict__ dst,
    const int* __restrict__ rank, const int* __restrict__ rowptr,
    const int* __restrict__ offs8, unsigned short* __restrict__ csr,
    int E, int N, int nbF,
    const float* __restrict__ x, const float* __restrict__ W,
    const float* __restrict__ b, __half* __restrict__ xt) {
  __shared__ __align__(16) float Wl[64 * 68];
  __shared__ __align__(16) float sc_all[8][8 * 68];
  if ((int)blockIdx.x < nbF) {
    int e = blockIdx.x * 512 + threadIdx.x;
    if (e >= E) return;
    int c = (e >> 8) & 7;  // matches k_histg's 256-thread mapping
    int d = dst[e];
    csr[rowptr[d] + offs8[(size_t)c * N + d] + rank[e]] = (unsigned short)src[e];
    return;
  }
  int bb = blockIdx.x - nbF;
  int tid = threadIdx.x, wid = tid >> 6, lane = tid & 63;
  int g = lane >> 3, sub = lane & 7;
  for (int i = tid; i < 4096; i += 512) Wl[(i >> 6) * 68 + (i & 63)] = W[i];
  __syncthreads();
  float hb8[8], hb2;
  hb_from_b(b, sub, hb8, hb2);

  int slot = bb * 64 + wid * 8 + g;
  bool valid = slot < N;
  int node = valid ? slot : 0;
  const float* row = x + (size_t)node * 64 + sub * 8;
  float4 v0 = ld4(row), v1 = ld4(row + 4);
  float xa[8] = {v0.x, v0.y, v0.z, v0.w, v1.x, v1.y, v1.z, v1.w};
  float p = 0.f;
#pragma unroll
  for (int j = 0; j < 8; ++j) p = fmaf(xa[j], xa[j], p);
  p = gr8(p);
  float na = fmaxf(fsqrt_(p), EPSF);
  float sc1 = lp_exp_log_scale(na);
  float t2[8];
#pragma unroll
  for (int j = 0; j < 8; ++j) t2[j] = sc1 * xa[j];
  float out8[8];
  linear_tail8(Wl, sc_all[wid], g, sub, lane, t2, hb8, hb2, out8);
  if (valid) st8h(xt, node, sub, out8);
}

// layer boundary: fp16 gather-mean -> hyp_agg -> act -> hyp_linear -> fp16.
__global__ void __launch_bounds__(512) k_gatherlin(
    const int* __restrict__ rowptr, const unsigned short* __restrict__ csr,
    const __half* __restrict__ xtp, const float* __restrict__ W,
    const float* __restrict__ b, __half* __restrict__ xt, int N) {
  __shared__ __align__(16) float Wl[64 * 68];
  __shared__ __align__(16) float sc_all[8][8 * 68];
  int tid = threadIdx.x, wid = tid >> 6, lane = tid & 63;
  int g = lane >> 3, sub = lane & 7;
  for (int i = tid; i < 4096; i += 512) Wl[(i >> 6) * 68 + (i & 63)] = W[i];
  __syncthreads();
  float hb8[8], hb2;
  hb_from_b(b, sub, hb8, hb2);

  int slot = blockIdx.x * 64 + wid * 8 + g;
  bool valid = slot < N;
  int node = valid ? slot : 0;
  int r0 = rowptr[node];
  int deg = valid ? (rowptr[node + 1] - r0) : 0;
  float acc[8] = {0.f, 0.f, 0.f, 0.f, 0.f, 0.f, 0.f, 0.f};
  gather8h(csr, xtp, r0, deg, g, sub, acc);
  float rdeg = frcp(fmaxf((float)deg, 1.f));
  float u[8];
#pragma unroll
  for (int j = 0; j < 8; ++j) u[j] = acc[j] * rdeg;
  float p = 0.f, q = 0.f;
#pragma unroll
  for (int j = 0; j < 8; ++j) {
    float w = (u[j] < 0.f) ? 0.04f : 1.f;
    p = fmaf(u[j], u[j], p);
    q = fmaf(w * u[j], u[j], q);
  }
  p = gr8(p); q = gr8(q);
  float nu = fmaxf(fsqrt_(p), EPSF);
  float s1 = lp_exp_log_scale(nu);
  float nt = fmaxf(s1 * fsqrt_(q), EPSF);
  float f = lp_exp_log_scale(nt) * s1;
  float t2[8];
#pragma unroll
  for (int j = 0; j < 8; ++j) t2[j] = f * u[j] * ((u[j] < 0.f) ? 0.2f : 1.f);
  float out8[8];
  linear_tail8(Wl, sc_all[wid], g, sub, lane, t2, hb8, hb2, out8);
  if (valid) st8h(xt, node, sub, out8);
}

// layer3 end: fp16 gather-mean -> hyp_agg -> logmap -> pool.  8 nodes/wave.
__global__ void __launch_bounds__(512) k_gpool(const int* __restrict__ rowptr,
                                               const unsigned short* __restrict__ csr,
                                               const __half* __restrict__ xtp,
                                               const int* __restrict__ batch,
                                               float* __restrict__ pooled, int N) {
  int tid = threadIdx.x, wid = tid >> 6, lane = tid & 63;
  int g = lane >> 3, sub = lane & 7;
  int slot = blockIdx.x * 64 + wid * 8 + g;
  bool valid = slot < N;
  int node = valid ? slot : 0;
  int r0 = rowptr[node];
  int deg = valid ? (rowptr[node + 1] - r0) : 0;
  float acc[8] = {0.f, 0.f, 0.f, 0.f, 0.f, 0.f, 0.f, 0.f};
  gather8h(csr, xtp, r0, deg, g, sub, acc);
  float rdeg = frcp(fmaxf((float)deg, 1.f));
  float u[8], p = 0.f;
#pragma unroll
  for (int j = 0; j < 8; ++j) {
    u[j] = acc[j] * rdeg;
    p = fmaf(u[j], u[j], p);
  }
  p = gr8(p);
  float nu = fmaxf(fsqrt_(p), EPSF);
  float s = lp_exp_log_scale(nu);
  float t8[8];
#pragma unroll
  for (int j = 0; j < 8; ++j) t8[j] = (valid ? s : 0.f) * u[j];
  int bs = batch[node];
  int b0 = __shfl(bs, 0, 64);
  bool uniform = __all(valid && bs == b0);
  if (uniform) {
#pragma unroll
    for (int j = 0; j < 8; ++j) {
      t8[j] += __shfl_xor(t8[j], 8, 64);
      t8[j] += __shfl_xor(t8[j], 16, 64);
      t8[j] += __shfl_xor(t8[j], 32, 64);
    }
    if (g == 0) {
#pragma unroll
      for (int j = 0; j < 8; ++j)
        atomicAdd(&pooled[(size_t)b0 * 64 + sub * 8 + j], t8[j]);
    }
  } else if (valid) {
#pragma unroll
    for (int j = 0; j < 8; ++j)
      atomicAdd(&pooled[(size_t)bs * 64 + sub * 8 + j], t8[j]);
  }
}

// head: per graph, 1 wave (precise; negligible cost)
__global__ void __launch_bounds__(64) k_final(const float* __restrict__ pooled,
                                              const float* __restrict__ cntg,
                                              const float* __restrict__ W4,
                                              const float* __restrict__ b4,
                                              float* __restrict__ out, int G) {
  int g = blockIdx.x;
  int lane = threadIdx.x;
  float u = pooled[(size_t)g * 64 + lane] / fmaxf(cntg[g], 1.0f);
  float n = fmaxf(sqrtf(rsum64(u * u)), EPSF);
  float e = tanhf(n) * u / n;
  float ne = fmaxf(sqrtf(rsum64(e * e)), EPSF);
  if (ne > MAXNORM) e *= MAXNORM / ne;
  float nn = fmaxf(sqrtf(rsum64(e * e)), EPSF);
  float t = atanhf(fminf(nn, MAXNORM)) * e / nn;

  int row = lane & 15;
  float acc = 0.f;
#pragma unroll
  for (int k = 0; k < 64; ++k) {
    float tk = __shfl(t, k, 64);
    acc = fmaf(W4[row * 64 + k], tk, acc);
  }
  float ny = fmaxf(sqrtf(rsum16(acc * acc)), EPSF);
  float hy = tanhf(ny) * acc / ny;
  float nh = fmaxf(sqrtf(rsum16(hy * hy)), EPSF);
  if (nh > MAXNORM) hy *= MAXNORM / nh;
  float bb = b4[row];
  float nb = fmaxf(sqrtf(rsum16(bb * bb)), EPSF);
  float hb = tanhf(nb) * bb / nb;
  float nhb = fmaxf(sqrtf(rsum16(hb * hb)), EPSF);
  if (nhb > MAXNORM) hb *= MAXNORM / nhb;
  float x2 = rsum16(hy * hy);
  float y2 = rsum16(hb * hb);
  float xy = rsum16(hy * hb);
  float num = (1.f + 2.f * xy + y2) * hy + (1.f - x2) * hb;
  float den = fmaxf(1.f + 2.f * xy + x2 * y2, EPSF);
  float r = num / den;
  float nr = fmaxf(sqrtf(rsum16(r * r)), EPSF);
  if (nr > MAXNORM) r *= MAXNORM / nr;
  if (lane < 16) out[(size_t)g * 16 + lane] = r;
}

extern "C" void kernel_launch(void* const* d_in, const int* in_sizes, int n_in,
                              void* d_out, int out_size, void* d_ws, size_t ws_size,
                              hipStream_t stream) {
  const float* x  = (const float*)d_in[0];
  const float* W1 = (const float*)d_in[1];
  const float* b1 = (const float*)d_in[2];
  const float* W2 = (const float*)d_in[3];
  const float* b2 = (const float*)d_in[4];
  const float* W3 = (const float*)d_in[5];
  const float* b3 = (const float*)d_in[6];
  const float* W4 = (const float*)d_in[7];
  const float* b4 = (const float*)d_in[8];
  const int* ei   = (const int*)d_in[9];
  const int* batch = (const int*)d_in[10];

  int N = in_sizes[0] / 64;
  int E = in_sizes[9] / 2;
  int G = out_size / 16;
  const int* src = ei;
  const int* dst = ei + E;

  float* ws = (float*)d_ws;
  __half* xtA   = (__half*)ws;                 // N*64 halves
  __half* xtB   = xtA + (size_t)N * 64;        // N*64 halves
  float* pooled = ws + (size_t)N * 64;         // G*64
  float* cntg   = pooled + (size_t)G * 64;     // G
  int* ip       = (int*)(cntg + G);
  int* deg8     = ip;                          // 8N
  int* done     = deg8 + (size_t)8 * N;        // 16 (zeroed with deg8)
  int* offs8    = done + 16;                   // 8N
  int* locscan  = offs8 + (size_t)8 * N;       // N
  int* rowptr   = locscan + N;                 // N+1
  int* partial  = rowptr + N + 1;              // 512 (pad)
  int* rank     = partial + 512;               // E
  unsigned short* csr = (unsigned short*)(rank + E);  // E ushorts
  float* out = (float*)d_out;

  int nbE = (E + 255) / 256;   // hist blocks (defines copy mapping (e>>8)&7)
  int nbG = (G + 255) / 256;
  int nbP = (N + 511) / 512;   // scan blocks
  int nbF = (E + 511) / 512;   // fill blocks (512-thread)
  int nbL = (N + 63) / 64;     // node blocks (512-thread, 64 nodes each)

  // one memset covers deg8 AND the last-block-finish counter
  hipMemsetAsync(deg8, 0, ((size_t)8 * N + 16) * sizeof(int), stream);

  k_histg<<<nbE + nbG, 256, 0, stream>>>(dst, deg8, rank, E, N, batch, cntg, G, nbE);
  k_scanR<<<nbP, 512, 0, stream>>>(deg8, offs8, locscan, rowptr, partial, done,
                                   pooled, N, E, G * 64);
  k_filllin<<<nbF + nbL, 512, 0, stream>>>(src, dst, rank, rowptr, offs8, csr,
                                           E, N, nbF, x, W1, b1, xtA);
  k_gatherlin<<<nbL, 512, 0, stream>>>(rowptr, csr, xtA, W2, b2, xtB, N);
  k_gatherlin<<<nbL, 512, 0, stream>>>(rowptr, csr, xtB, W3, b3, xtA, N);
  k_gpool<<<nbL, 512, 0, stream>>>(rowptr, csr, xtA, batch, pooled, N);
  k_final<<<G, 64, 0, stream>>>(pooled, cntg, W4, b4, out, G);
}

// Round 17
// 174.523 us; speedup vs baseline: 2.5262x; 1.1548x over previous
//
#include <hip/hip_runtime.h>
#include <hip/hip_fp16.h>

#define EPSF 1e-7f
#define MAXNORM (1.0f - 1e-5f)

__device__ __forceinline__ float rsum64(float v) {
#pragma unroll
  for (int m = 32; m; m >>= 1) v += __shfl_xor(v, m, 64);
  return v;
}
__device__ __forceinline__ float rsum16(float v) {
#pragma unroll
  for (int m = 8; m; m >>= 1) v += __shfl_xor(v, m, 64);
  return v;
}
// 8-lane group reduce (3 levels) — serves 8 nodes per wave at once
__device__ __forceinline__ float gr8(float v) {
  v += __shfl_xor(v, 1, 64);
  v += __shfl_xor(v, 2, 64);
  v += __shfl_xor(v, 4, 64);
  return v;
}

__device__ __forceinline__ float frcp(float x) { return __builtin_amdgcn_rcpf(x); }
__device__ __forceinline__ float fsqrt_(float x) { return __builtin_amdgcn_sqrtf(x); }
__device__ __forceinline__ float tanh_fast(float x) {
  x = fminf(x, 20.f);
  float e = __builtin_amdgcn_exp2f(x * 2.88539008178f);  // e^{2x}
  return (e - 1.f) * frcp(e + 1.f);
}
__device__ __forceinline__ float atanh_fast(float x) {
  return 0.34657359028f * __builtin_amdgcn_logf((1.f + x) * frcp(1.f - x));
}
// logmap0(proj(expmap0(u))) == f(nu) * u
__device__ __forceinline__ float lp_exp_log_scale(float nu) {
  float te = tanh_fast(nu);
  float tec = fminf(fmaxf(te, EPSF), MAXNORM);
  return atanh_fast(tec) * frcp(fmaxf(te, EPSF)) * te * frcp(nu);
}

__device__ __forceinline__ float4 ld4(const float* p) {
  return *reinterpret_cast<const float4*>(p);
}

// hb8/hb2 = proj(expmap0(b)) in 8-dim layout, computed per-thread (~20 VALU).
__device__ __forceinline__ void hb_from_b(const float* __restrict__ b, int sub,
                                          float hb8[8], float& hb2) {
  float4 b0 = ld4(b + sub * 8), b1 = ld4(b + sub * 8 + 4);
  float bb8[8] = {b0.x, b0.y, b0.z, b0.w, b1.x, b1.y, b1.z, b1.w};
  float p = 0.f;
#pragma unroll
  for (int j = 0; j < 8; ++j) p = fmaf(bb8[j], bb8[j], p);
  p = gr8(p);
  float nb = fmaxf(fsqrt_(p), EPSF);
  float cb = fminf(tanh_fast(nb), MAXNORM);
  float kb = cb * frcp(nb);
#pragma unroll
  for (int j = 0; j < 8; ++j) hb8[j] = kb * bb8[j];
  hb2 = cb * cb;
}

// ---- 8-node gather over fp16 rows, node-major ushort csr.
// Software-pipelined: next chunk's 8 csr indices load BEFORE current chunk's
// row processing.
__device__ __forceinline__ void gather8h(const unsigned short* __restrict__ csr,
                                         const __half* __restrict__ xtp,
                                         int r0, int deg, int g, int sub,
                                         float acc[8]) {
  const uint4* xt4 = reinterpret_cast<const uint4*>(xtp);
  int lb = g << 3;
  int cur = (sub < deg) ? (int)csr[r0 + sub] : 0;
  for (int j0 = 0; j0 < deg; j0 += 8) {
    int nj = j0 + 8;
    int nxt = (nj + sub < deg) ? (int)csr[r0 + nj + sub] : 0;
#pragma unroll
    for (int m = 0; m < 8; ++m) {
      int idx = __shfl(cur, lb + m, 64);
      float msk = (j0 + m < deg) ? 1.f : 0.f;
      union { uint4 u; __half2 h[4]; } U;
      U.u = xt4[(size_t)idx * 8 + sub];
      float2 f0 = __half22float2(U.h[0]);
      float2 f1 = __half22float2(U.h[1]);
      float2 f2 = __half22float2(U.h[2]);
      float2 f3 = __half22float2(U.h[3]);
      acc[0] = fmaf(msk, f0.x, acc[0]); acc[1] = fmaf(msk, f0.y, acc[1]);
      acc[2] = fmaf(msk, f1.x, acc[2]); acc[3] = fmaf(msk, f1.y, acc[3]);
      acc[4] = fmaf(msk, f2.x, acc[4]); acc[5] = fmaf(msk, f2.y, acc[5]);
      acc[6] = fmaf(msk, f3.x, acc[6]); acc[7] = fmaf(msk, f3.y, acc[7]);
    }
    cur = nxt;
  }
}

// store 8 f32 dims as 8 fp16 (one uint4 per lane)
__device__ __forceinline__ void st8h(__half* __restrict__ xt, int node, int sub,
                                     const float o[8]) {
  union { uint4 u; __half2 h[4]; } U;
  U.h[0] = __floats2half2_rn(o[0], o[1]);
  U.h[1] = __floats2half2_rn(o[2], o[3]);
  U.h[2] = __floats2half2_rn(o[4], o[5]);
  U.h[3] = __floats2half2_rn(o[6], o[7]);
  reinterpret_cast<uint4*>(xt)[(size_t)node * 8 + sub] = U.u;
}

// ---- matvec + mobius-bias + proj + logmap0, 8 nodes/wave, 8-dim layout.
__device__ __forceinline__ void linear_tail8(
    const float* __restrict__ Wl, float* __restrict__ sc, int g, int sub,
    int lane, const float t2[8], const float hb8[8], float hb2, float out8[8]) {
  float4* sw = reinterpret_cast<float4*>(sc + g * 68 + sub * 8);
  sw[0] = make_float4(t2[0], t2[1], t2[2], t2[3]);
  sw[1] = make_float4(t2[4], t2[5], t2[6], t2[7]);
  float y[8] = {0.f, 0.f, 0.f, 0.f, 0.f, 0.f, 0.f, 0.f};
  const float4* Wrow = reinterpret_cast<const float4*>(Wl + lane * 68);
#pragma unroll
  for (int q = 0; q < 16; ++q) {
    float4 w = Wrow[q];
#pragma unroll
    for (int g2 = 0; g2 < 8; ++g2) {
      float4 tq = *reinterpret_cast<const float4*>(sc + g2 * 68 + q * 4);
      y[g2] = fmaf(w.x, tq.x, fmaf(w.y, tq.y, fmaf(w.z, tq.z, fmaf(w.w, tq.w, y[g2]))));
    }
  }
#pragma unroll
  for (int g2 = 0; g2 < 8; ++g2) sc[g2 * 68 + lane] = y[g2];
  float4 r0 = *reinterpret_cast<const float4*>(sc + g * 68 + sub * 8);
  float4 r1 = *reinterpret_cast<const float4*>(sc + g * 68 + sub * 8 + 4);
  float yv[8] = {r0.x, r0.y, r0.z, r0.w, r1.x, r1.y, r1.z, r1.w};
  float p1 = 0.f, p2 = 0.f;
#pragma unroll
  for (int j = 0; j < 8; ++j) {
    p1 = fmaf(yv[j], yv[j], p1);
    p2 = fmaf(yv[j], hb8[j], p2);
  }
  p1 = gr8(p1); p2 = gr8(p2);
  float ny = fmaxf(fsqrt_(p1), EPSF);
  float cy = fminf(tanh_fast(ny), MAXNORM);
  float k = cy * frcp(ny);
  float xy = k * p2;
  float x2 = cy * cy;
  float aa = 1.f + 2.f * xy + hb2;
  float cc = 1.f - x2;
  float den = fmaxf(1.f + 2.f * xy + x2 * hb2, EPSF);
  float rd = frcp(den);
  float nr2 = (aa * aa * x2 + 2.f * aa * cc * xy + cc * cc * hb2) * rd * rd;
  float nr = fmaxf(fsqrt_(nr2), EPSF);
  float s = atanh_fast(fminf(nr, MAXNORM)) * frcp(nr);
  float sk = s * rd;
#pragma unroll
  for (int j = 0; j < 8; ++j) out8[j] = sk * (aa * k * yv[j] + cc * hb8[j]);
}

// ---- fused: XCD-private hist + rank capture | graph sizes (block-range split)
__global__ void __launch_bounds__(256) k_histg(
    const int* __restrict__ dst, int* __restrict__ deg8, int* __restrict__ rank,
    int E, int N, const int* __restrict__ batch, float* __restrict__ cntg,
    int G, int nbE) {
  if ((int)blockIdx.x < nbE) {
    int e = blockIdx.x * 256 + threadIdx.x;
    if (e >= E) return;
    int c = (e >> 8) & 7;
    rank[e] = atomicAdd(&deg8[(size_t)c * N + dst[e]], 1);
  } else {
    int g = (blockIdx.x - nbE) * 256 + threadIdx.x;
    if (g >= G) return;
    int lo = 0, hi = N;
    while (lo < hi) { int mid = (lo + hi) >> 1; if (batch[mid] < g) lo = mid + 1; else hi = mid; }
    int lb = lo;
    lo = 0; hi = N; int g1 = g + 1;
    while (lo < hi) { int mid = (lo + hi) >> 1; if (batch[mid] < g1) lo = mid + 1; else hi = mid; }
    cntg[g] = (float)(lo - lb);
  }
}

// ---- fused red8 + scanA: per-node 8-copy reduce + offs8, then block scan.
__global__ void __launch_bounds__(256) k_scanAR(const int* __restrict__ deg8,
                                                int* __restrict__ offs8,
                                                int* __restrict__ locscan,
                                                int* __restrict__ partial, int N) {
  __shared__ int buf[256];
  int i = blockIdx.x * 256 + threadIdx.x;
  int s = 0;
  if (i < N) {
#pragma unroll
    for (int k = 0; k < 8; ++k) {
      int v = deg8[(size_t)k * N + i];
      offs8[(size_t)k * N + i] = s;
      s += v;
    }
  }
  int v0 = s;
  buf[threadIdx.x] = v0;
  __syncthreads();
#pragma unroll
  for (int off = 1; off < 256; off <<= 1) {
    int t = (threadIdx.x >= off) ? buf[threadIdx.x - off] : 0;
    __syncthreads();
    buf[threadIdx.x] += t;
    __syncthreads();
  }
  if (i < N) locscan[i] = buf[threadIdx.x] - v0;
  if (threadIdx.x == 255) partial[blockIdx.x] = buf[255];
}

__global__ void __launch_bounds__(256) k_scanB(int* __restrict__ partial, int nb) {
  __shared__ int buf[256];
  int carry = 0;
  for (int base = 0; base < nb; base += 256) {
    int i = base + threadIdx.x;
    int v = (i < nb) ? partial[i] : 0;
    buf[threadIdx.x] = v;
    __syncthreads();
#pragma unroll
    for (int off = 1; off < 256; off <<= 1) {
      int t = (threadIdx.x >= off) ? buf[threadIdx.x - off] : 0;
      __syncthreads();
      buf[threadIdx.x] += t;
      __syncthreads();
    }
    if (i < nb) partial[i] = carry + buf[threadIdx.x] - v;
    int total = buf[255];
    __syncthreads();
    carry += total;
  }
}

__global__ void __launch_bounds__(256) k_scanC(const int* __restrict__ locscan,
                                               const int* __restrict__ partial,
                                               int* __restrict__ rowptr, int N, int E) {
  int i = blockIdx.x * 256 + threadIdx.x;
  if (i < N) rowptr[i] = locscan[i] + partial[blockIdx.x];
  if (i == 0) rowptr[N] = E;
}

// ---- fused: atomic-free CSR fill (blocks < nbF) | layer-1 linear (rest).
__global__ void __launch_bounds__(512) k_filllin(
    const int* __restrict__ src, const int* __restrict__ dst,
    const int* __restrict__ rank, const int* __restrict__ rowptr,
    const int* __restrict__ offs8, unsigned short* __restrict__ csr,
    int E, int N, int nbF,
    const float* __restrict__ x, const float* __restrict__ W,
    const float* __restrict__ b, __half* __restrict__ xt) {
  __shared__ __align__(16) float Wl[64 * 68];
  __shared__ __align__(16) float sc_all[8][8 * 68];
  if ((int)blockIdx.x < nbF) {
    int e = blockIdx.x * 512 + threadIdx.x;
    if (e >= E) return;
    int c = (e >> 8) & 7;  // matches k_histg's 256-thread mapping
    int d = dst[e];
    csr[rowptr[d] + offs8[(size_t)c * N + d] + rank[e]] = (unsigned short)src[e];
    return;
  }
  int bb = blockIdx.x - nbF;
  int tid = threadIdx.x, wid = tid >> 6, lane = tid & 63;
  int g = lane >> 3, sub = lane & 7;
  for (int i = tid; i < 4096; i += 512) Wl[(i >> 6) * 68 + (i & 63)] = W[i];
  __syncthreads();
  float hb8[8], hb2;
  hb_from_b(b, sub, hb8, hb2);

  int slot = bb * 64 + wid * 8 + g;
  bool valid = slot < N;
  int node = valid ? slot : 0;
  const float* row = x + (size_t)node * 64 + sub * 8;
  float4 v0 = ld4(row), v1 = ld4(row + 4);
  float xa[8] = {v0.x, v0.y, v0.z, v0.w, v1.x, v1.y, v1.z, v1.w};
  float p = 0.f;
#pragma unroll
  for (int j = 0; j < 8; ++j) p = fmaf(xa[j], xa[j], p);
  p = gr8(p);
  float na = fmaxf(fsqrt_(p), EPSF);
  float sc1 = lp_exp_log_scale(na);
  float t2[8];
#pragma unroll
  for (int j = 0; j < 8; ++j) t2[j] = sc1 * xa[j];
  float out8[8];
  linear_tail8(Wl, sc_all[wid], g, sub, lane, t2, hb8, hb2, out8);
  if (valid) st8h(xt, node, sub, out8);
}

// layer boundary: fp16 gather-mean -> hyp_agg -> act -> hyp_linear -> fp16.
__global__ void __launch_bounds__(512) k_gatherlin(
    const int* __restrict__ rowptr, const unsigned short* __restrict__ csr,
    const __half* __restrict__ xtp, const float* __restrict__ W,
    const float* __restrict__ b, __half* __restrict__ xt, int N) {
  __shared__ __align__(16) float Wl[64 * 68];
  __shared__ __align__(16) float sc_all[8][8 * 68];
  int tid = threadIdx.x, wid = tid >> 6, lane = tid & 63;
  int g = lane >> 3, sub = lane & 7;
  for (int i = tid; i < 4096; i += 512) Wl[(i >> 6) * 68 + (i & 63)] = W[i];
  __syncthreads();
  float hb8[8], hb2;
  hb_from_b(b, sub, hb8, hb2);

  int slot = blockIdx.x * 64 + wid * 8 + g;
  bool valid = slot < N;
  int node = valid ? slot : 0;
  int r0 = rowptr[node];
  int deg = valid ? (rowptr[node + 1] - r0) : 0;
  float acc[8] = {0.f, 0.f, 0.f, 0.f, 0.f, 0.f, 0.f, 0.f};
  gather8h(csr, xtp, r0, deg, g, sub, acc);
  float rdeg = frcp(fmaxf((float)deg, 1.f));
  float u[8];
#pragma unroll
  for (int j = 0; j < 8; ++j) u[j] = acc[j] * rdeg;
  float p = 0.f, q = 0.f;
#pragma unroll
  for (int j = 0; j < 8; ++j) {
    float w = (u[j] < 0.f) ? 0.04f : 1.f;
    p = fmaf(u[j], u[j], p);
    q = fmaf(w * u[j], u[j], q);
  }
  p = gr8(p); q = gr8(q);
  float nu = fmaxf(fsqrt_(p), EPSF);
  float s1 = lp_exp_log_scale(nu);
  float nt = fmaxf(s1 * fsqrt_(q), EPSF);
  float f = lp_exp_log_scale(nt) * s1;
  float t2[8];
#pragma unroll
  for (int j = 0; j < 8; ++j) t2[j] = f * u[j] * ((u[j] < 0.f) ? 0.2f : 1.f);
  float out8[8];
  linear_tail8(Wl, sc_all[wid], g, sub, lane, t2, hb8, hb2, out8);
  if (valid) st8h(xt, node, sub, out8);
}

// layer3 end: fp16 gather-mean -> hyp_agg -> logmap -> pool.  8 nodes/wave.
__global__ void __launch_bounds__(512) k_gpool(const int* __restrict__ rowptr,
                                               const unsigned short* __restrict__ csr,
                                               const __half* __restrict__ xtp,
                                               const int* __restrict__ batch,
                                               float* __restrict__ pooled, int N) {
  int tid = threadIdx.x, wid = tid >> 6, lane = tid & 63;
  int g = lane >> 3, sub = lane & 7;
  int slot = blockIdx.x * 64 + wid * 8 + g;
  bool valid = slot < N;
  int node = valid ? slot : 0;
  int r0 = rowptr[node];
  int deg = valid ? (rowptr[node + 1] - r0) : 0;
  float acc[8] = {0.f, 0.f, 0.f, 0.f, 0.f, 0.f, 0.f, 0.f};
  gather8h(csr, xtp, r0, deg, g, sub, acc);
  float rdeg = frcp(fmaxf((float)deg, 1.f));
  float u[8], p = 0.f;
#pragma unroll
  for (int j = 0; j < 8; ++j) {
    u[j] = acc[j] * rdeg;
    p = fmaf(u[j], u[j], p);
  }
  p = gr8(p);
  float nu = fmaxf(fsqrt_(p), EPSF);
  float s = lp_exp_log_scale(nu);
  float t8[8];
#pragma unroll
  for (int j = 0; j < 8; ++j) t8[j] = (valid ? s : 0.f) * u[j];
  int bs = batch[node];
  int b0 = __shfl(bs, 0, 64);
  bool uniform = __all(valid && bs == b0);
  if (uniform) {
#pragma unroll
    for (int j = 0; j < 8; ++j) {
      t8[j] += __shfl_xor(t8[j], 8, 64);
      t8[j] += __shfl_xor(t8[j], 16, 64);
      t8[j] += __shfl_xor(t8[j], 32, 64);
    }
    if (g == 0) {
#pragma unroll
      for (int j = 0; j < 8; ++j)
        atomicAdd(&pooled[(size_t)b0 * 64 + sub * 8 + j], t8[j]);
    }
  } else if (valid) {
#pragma unroll
    for (int j = 0; j < 8; ++j)
      atomicAdd(&pooled[(size_t)bs * 64 + sub * 8 + j], t8[j]);
  }
}

// head: per graph, 1 wave (precise; negligible cost)
__global__ void __launch_bounds__(64) k_final(const float* __restrict__ pooled,
                                              const float* __restrict__ cntg,
                                              const float* __restrict__ W4,
                                              const float* __restrict__ b4,
                                              float* __restrict__ out, int G) {
  int g = blockIdx.x;
  int lane = threadIdx.x;
  float u = pooled[(size_t)g * 64 + lane] / fmaxf(cntg[g], 1.0f);
  float n = fmaxf(sqrtf(rsum64(u * u)), EPSF);
  float e = tanhf(n) * u / n;
  float ne = fmaxf(sqrtf(rsum64(e * e)), EPSF);
  if (ne > MAXNORM) e *= MAXNORM / ne;
  float nn = fmaxf(sqrtf(rsum64(e * e)), EPSF);
  float t = atanhf(fminf(nn, MAXNORM)) * e / nn;

  int row = lane & 15;
  float acc = 0.f;
#pragma unroll
  for (int k = 0; k < 64; ++k) {
    float tk = __shfl(t, k, 64);
    acc = fmaf(W4[row * 64 + k], tk, acc);
  }
  float ny = fmaxf(sqrtf(rsum16(acc * acc)), EPSF);
  float hy = tanhf(ny) * acc / ny;
  float nh = fmaxf(sqrtf(rsum16(hy * hy)), EPSF);
  if (nh > MAXNORM) hy *= MAXNORM / nh;
  float bb = b4[row];
  float nb = fmaxf(sqrtf(rsum16(bb * bb)), EPSF);
  float hb = tanhf(nb) * bb / nb;
  float nhb = fmaxf(sqrtf(rsum16(hb * hb)), EPSF);
  if (nhb > MAXNORM) hb *= MAXNORM / nhb;
  float x2 = rsum16(hy * hy);
  float y2 = rsum16(hb * hb);
  float xy = rsum16(hy * hb);
  float num = (1.f + 2.f * xy + y2) * hy + (1.f - x2) * hb;
  float den = fmaxf(1.f + 2.f * xy + x2 * y2, EPSF);
  float r = num / den;
  float nr = fmaxf(sqrtf(rsum16(r * r)), EPSF);
  if (nr > MAXNORM) r *= MAXNORM / nr;
  if (lane < 16) out[(size_t)g * 16 + lane] = r;
}

extern "C" void kernel_launch(void* const* d_in, const int* in_sizes, int n_in,
                              void* d_out, int out_size, void* d_ws, size_t ws_size,
                              hipStream_t stream) {
  const float* x  = (const float*)d_in[0];
  const float* W1 = (const float*)d_in[1];
  const float* b1 = (const float*)d_in[2];
  const float* W2 = (const float*)d_in[3];
  const float* b2 = (const float*)d_in[4];
  const float* W3 = (const float*)d_in[5];
  const float* b3 = (const float*)d_in[6];
  const float* W4 = (const float*)d_in[7];
  const float* b4 = (const float*)d_in[8];
  const int* ei   = (const int*)d_in[9];
  const int* batch = (const int*)d_in[10];

  int N = in_sizes[0] / 64;
  int E = in_sizes[9] / 2;
  int G = out_size / 16;
  const int* src = ei;
  const int* dst = ei + E;

  float* ws = (float*)d_ws;
  __half* xtA   = (__half*)ws;                 // N*64 halves
  __half* xtB   = xtA + (size_t)N * 64;        // N*64 halves
  float* pooled = ws + (size_t)N * 64;         // G*64
  float* cntg   = pooled + (size_t)G * 64;     // G
  int* ip       = (int*)(cntg + G);
  int* deg8     = ip;                          // 8N
  int* offs8    = deg8 + (size_t)8 * N;        // 8N
  int* locscan  = offs8 + (size_t)8 * N;       // N
  int* rowptr   = locscan + N;                 // N+1
  int* partial  = rowptr + N + 1;              // 256 (pad)
  int* rank     = partial + 256;               // E
  unsigned short* csr = (unsigned short*)(rank + E);  // E ushorts
  float* out = (float*)d_out;

  int nbE = (E + 255) / 256;   // hist blocks (defines copy mapping (e>>8)&7)
  int nbG = (G + 255) / 256;
  int nbN = (N + 255) / 256;
  int nbF = (E + 511) / 512;   // fill blocks (512-thread)
  int nbL = (N + 63) / 64;     // node blocks (512-thread, 64 nodes each)

  hipMemsetAsync(deg8, 0, (size_t)8 * N * sizeof(int), stream);
  hipMemsetAsync(pooled, 0, (size_t)G * 64 * sizeof(float), stream);

  k_histg<<<nbE + nbG, 256, 0, stream>>>(dst, deg8, rank, E, N, batch, cntg, G, nbE);
  k_scanAR<<<nbN, 256, 0, stream>>>(deg8, offs8, locscan, partial, N);
  k_scanB<<<1, 256, 0, stream>>>(partial, nbN);
  k_scanC<<<nbN, 256, 0, stream>>>(locscan, partial, rowptr, N, E);
  k_filllin<<<nbF + nbL, 512, 0, stream>>>(src, dst, rank, rowptr, offs8, csr,
                                           E, N, nbF, x, W1, b1, xtA);
  k_gatherlin<<<nbL, 512, 0, stream>>>(rowptr, csr, xtA, W2, b2, xtB, N);
  k_gatherlin<<<nbL, 512, 0, stream>>>(rowptr, csr, xtB, W3, b3, xtA, N);
  k_gpool<<<nbL, 512, 0, stream>>>(rowptr, csr, xtA, batch, pooled, N);
  k_final<<<G, 64, 0, stream>>>(pooled, cntg, W4, b4, out, G);
}